// Round 6
// baseline (204.683 us; speedup 1.0000x reference)
//
#include <hip/hip_runtime.h>

#define BATCH 2
#define L_SEQ 2048
#define DI 2048
#define NROW (BATCH * L_SEQ)   // 4096
#define E_DIM 96
#define RNK 64                 // DT_RANK
#define NST 16                 // D_STATE
#define NCH 128                // chunks
#define CL 16                  // chunk length (NCH*CL == L_SEQ)
#define SPLITK 16              // K1 split-K factor
#define KSL (DI / SPLITK)      // 128 k per split

// ---------------- workspace layout (floats) ----------------
// xdbl  : [NROW][96]                              393216
// region2 (overlaid, disjoint lifetimes):
//   partials : [SPLITK][NROW][96]   6291456  (K1 -> reduce, then dead)
//   hloc     : [BATCH][NCH][DI][16] 8388608  (S1 -> S3)
//   dsum     : [BATCH][NCH][DI]      524288
#define WS_XDBL 0
#define WS_PART 393216
#define WS_HLOC 393216
#define WS_DSUM (393216 + 8388608)

__device__ __forceinline__ float softplusf(float z) {
    return fmaxf(z, 0.f) + __logf(1.f + __expf(-fabsf(z)));
}

// ===== K1a: partial[s] = x[:, ksl] @ W^T slice =====
__global__ __launch_bounds__(256) void gemm_xproj_part(const float* __restrict__ x,
                                                       const float* __restrict__ Wx,
                                                       float* __restrict__ part) {
    __shared__ float xs[32][68];    // [k][row], pitch 272B (16B aligned)
    __shared__ float wsh[32][100];  // [k][e],  pitch 400B (16B aligned)
    const int tid = threadIdx.x;
    const int r0 = blockIdx.x * 64;
    const int kbase0 = blockIdx.y * KSL;
    const int rg = tid >> 4;   // 16 groups of 4 rows
    const int cg = tid & 15;   // 16 groups of 6 cols

    float acc[4][6];
#pragma unroll
    for (int i = 0; i < 4; i++)
#pragma unroll
        for (int j = 0; j < 6; j++) acc[i][j] = 0.f;

    for (int kt = 0; kt < KSL / 32; kt++) {
        const int kb = kbase0 + kt * 32;
#pragma unroll
        for (int rep = 0; rep < 2; rep++) {
            int i = rep * 256 + tid;   // 0..511
            int row = i >> 3;          // 0..63
            int kq = i & 7;
            float4 v = *(const float4*)&x[(long)(r0 + row) * DI + kb + kq * 4];
            xs[kq * 4 + 0][row] = v.x;
            xs[kq * 4 + 1][row] = v.y;
            xs[kq * 4 + 2][row] = v.z;
            xs[kq * 4 + 3][row] = v.w;
        }
#pragma unroll
        for (int rep = 0; rep < 3; rep++) {
            int i = rep * 256 + tid;   // 0..767
            int e = i >> 3;            // 0..95
            int kq = i & 7;
            float4 v = *(const float4*)&Wx[(long)e * DI + kb + kq * 4];
            wsh[kq * 4 + 0][e] = v.x;
            wsh[kq * 4 + 1][e] = v.y;
            wsh[kq * 4 + 2][e] = v.z;
            wsh[kq * 4 + 3][e] = v.w;
        }
        __syncthreads();
#pragma unroll 8
        for (int k = 0; k < 32; k++) {
            float xr[4], wr[6];
#pragma unroll
            for (int i = 0; i < 4; i++) xr[i] = xs[k][rg * 4 + i];
#pragma unroll
            for (int j = 0; j < 6; j++) wr[j] = wsh[k][cg * 6 + j];
#pragma unroll
            for (int i = 0; i < 4; i++)
#pragma unroll
                for (int j = 0; j < 6; j++) acc[i][j] = fmaf(xr[i], wr[j], acc[i][j]);
        }
        __syncthreads();
    }
    const long sbase = (long)blockIdx.y * NROW * E_DIM;
#pragma unroll
    for (int i = 0; i < 4; i++) {
        long rowb = sbase + (long)(r0 + rg * 4 + i) * E_DIM + cg * 6;
#pragma unroll
        for (int j = 0; j < 6; j++) part[rowb + j] = acc[i][j];
    }
}

// ===== K1b: xdbl = sum over splits (float4-vectorized) =====
__global__ __launch_bounds__(256) void xproj_reduce(const float* __restrict__ part,
                                                    float* __restrict__ xdbl) {
    const int i4 = blockIdx.x * 256 + threadIdx.x;   // 98304 float4 outputs
    const float4* p4 = (const float4*)part;
    float4 s = p4[i4];
#pragma unroll
    for (int sp = 1; sp < SPLITK; sp++) {
        float4 v = p4[(long)sp * (NROW * E_DIM / 4) + i4];
        s.x += v.x; s.y += v.y; s.z += v.z; s.w += v.w;
    }
    ((float4*)xdbl)[i4] = s;
}

// ===== K2: delta = softplus(dlt @ Wdt^T + b) -> d_out =====
__global__ __launch_bounds__(256) void gemm_dt(const float* __restrict__ xdbl,
                                               const float* __restrict__ Wdt,
                                               const float* __restrict__ b_dt,
                                               float* __restrict__ delta) {
    __shared__ float dl[32][68];    // [k][row], pitch 272B
    __shared__ float wt[32][132];   // [k][col], pitch 528B
    const int tid = threadIdx.x;
    const int row0 = blockIdx.x * 64;
    const int d0 = blockIdx.y * 128;
    const int rg = tid >> 5;    // 8 groups of 8 rows
    const int cg = tid & 31;    // 32 groups of 4 cols

    float acc[8][4];
#pragma unroll
    for (int i = 0; i < 8; i++)
#pragma unroll
        for (int j = 0; j < 4; j++) acc[i][j] = 0.f;

    for (int kt = 0; kt < 2; kt++) {
        const int kb = kt * 32;
#pragma unroll
        for (int rep = 0; rep < 2; rep++) {
            int i = rep * 256 + tid;
            int row = i >> 3;          // 0..63
            int kq = i & 7;
            float4 v = *(const float4*)&xdbl[(long)(row0 + row) * E_DIM + kb + kq * 4];
            dl[kq * 4 + 0][row] = v.x;
            dl[kq * 4 + 1][row] = v.y;
            dl[kq * 4 + 2][row] = v.z;
            dl[kq * 4 + 3][row] = v.w;
        }
#pragma unroll
        for (int rep = 0; rep < 4; rep++) {
            int i = rep * 256 + tid;
            int col = i >> 3;          // 0..127
            int kq = i & 7;
            float4 v = *(const float4*)&Wdt[(long)(d0 + col) * RNK + kb + kq * 4];
            wt[kq * 4 + 0][col] = v.x;
            wt[kq * 4 + 1][col] = v.y;
            wt[kq * 4 + 2][col] = v.z;
            wt[kq * 4 + 3][col] = v.w;
        }
        __syncthreads();
#pragma unroll 8
        for (int k = 0; k < 32; k++) {
            float xr[8], wr[4];
#pragma unroll
            for (int i = 0; i < 8; i++) xr[i] = dl[k][rg * 8 + i];
#pragma unroll
            for (int j = 0; j < 4; j++) wr[j] = wt[k][cg * 4 + j];
#pragma unroll
            for (int i = 0; i < 8; i++)
#pragma unroll
                for (int j = 0; j < 4; j++) acc[i][j] = fmaf(xr[i], wr[j], acc[i][j]);
        }
        __syncthreads();
    }

    float4 bb = *(const float4*)&b_dt[d0 + cg * 4];
#pragma unroll
    for (int i = 0; i < 8; i++) {
        int row = row0 + rg * 8 + i;
        float4 o;
        o.x = softplusf(acc[i][0] + bb.x);
        o.y = softplusf(acc[i][1] + bb.y);
        o.z = softplusf(acc[i][2] + bb.z);
        o.w = softplusf(acc[i][3] + bb.w);
        *(float4*)&delta[(long)row * DI + d0 + cg * 4] = o;
    }
}

// ===== S1: chunk-local carries; B staged in LDS; prefetch depth 2 =====
__global__ __launch_bounds__(256) void scan_carry(const float* __restrict__ x,
                                                  const float* __restrict__ delta,
                                                  const float* __restrict__ xdbl,
                                                  const float* __restrict__ A_log,
                                                  float* __restrict__ hloc,
                                                  float* __restrict__ dsumb) {
    __shared__ float bs[CL * NST];   // 1 KB
    const int tid = threadIdx.x;
    const int d = blockIdx.x * 256 + tid;
    const int c = blockIdx.y;
    const int b = blockIdx.z;
    const int row0 = b * L_SEQ + c * CL;

    if (tid < CL * NST / 4) {   // 64 float4
        int row = tid >> 2, q = tid & 3;
        ((float4*)bs)[tid] = *(const float4*)&xdbl[(long)(row0 + row) * E_DIM + 64 + q * 4];
    }
    __syncthreads();

    float A[16];
#pragma unroll
    for (int q = 0; q < 4; q++) {
        float4 v = *(const float4*)&A_log[(long)d * NST + q * 4];
        A[q * 4 + 0] = -__expf(v.x);
        A[q * 4 + 1] = -__expf(v.y);
        A[q * 4 + 2] = -__expf(v.z);
        A[q * 4 + 3] = -__expf(v.w);
    }
    float h[16];
#pragma unroll
    for (int n = 0; n < 16; n++) h[n] = 0.f;
    float dsum = 0.f;

    long idx = (long)row0 * DI + d;
    float d0v = delta[idx],      x0v = x[idx];
    float d1v = delta[idx + DI], x1v = x[idx + DI];
#pragma unroll
    for (int ll = 0; ll < CL; ll++) {
        float dc = d0v, xc = x0v;
        d0v = d1v; x0v = x1v;
        if (ll + 2 < CL) { d1v = delta[idx + 2 * DI]; x1v = x[idx + 2 * DI]; }
        float du = dc * xc;
        float bl[16];
#pragma unroll
        for (int q = 0; q < 4; q++) {
            float4 v = *(const float4*)&bs[ll * NST + q * 4];   // broadcast
            bl[q * 4 + 0] = v.x; bl[q * 4 + 1] = v.y; bl[q * 4 + 2] = v.z; bl[q * 4 + 3] = v.w;
        }
#pragma unroll
        for (int n = 0; n < 16; n++)
            h[n] = fmaf(__expf(dc * A[n]), h[n], du * bl[n]);
        dsum += dc;
        idx += DI;
    }

    const long cb = ((long)(b * NCH + c) * DI + d);
#pragma unroll
    for (int q = 0; q < 4; q++)
        *(float4*)&hloc[cb * 16 + q * 4] =
            make_float4(h[q * 4], h[q * 4 + 1], h[q * 4 + 2], h[q * 4 + 3]);
    dsumb[cb] = dsum;
}

// ===== S2: prefix over chunks; hloc becomes chunk-entry state =====
__global__ __launch_bounds__(256) void scan_prefix(const float* __restrict__ A_log,
                                                   float* __restrict__ hloc,
                                                   const float* __restrict__ dsumb) {
    const int g = blockIdx.x * 256 + threadIdx.x;   // 65536 threads
    const int n = g & 15;
    const int d = (g >> 4) & (DI - 1);
    const int b = g >> 15;
    const float An = -__expf(A_log[(long)d * NST + n]);
    float hc = 0.f;
#pragma unroll 8
    for (int c = 0; c < NCH; c++) {
        const long cb = ((long)(b * NCH + c) * DI + d);
        float hl = hloc[cb * 16 + n];
        float dsv = dsumb[cb];
        hloc[cb * 16 + n] = hc;               // overwrite with entry state
        hc = fmaf(__expf(An * dsv), hc, hl);  // state at end of chunk c
    }
}

// ===== S3: output pass — B/C staged in LDS; prefetch depth 2 =====
__global__ __launch_bounds__(256) void scan_out(const float* __restrict__ x,
                                                const float* __restrict__ xdbl,
                                                const float* __restrict__ A_log,
                                                const float* __restrict__ Dp,
                                                const float* __restrict__ hloc,
                                                float* __restrict__ out) {
    __shared__ float bs[CL * NST];
    __shared__ float cs[CL * NST];
    const int tid = threadIdx.x;
    const int d = blockIdx.x * 256 + tid;
    const int c = blockIdx.y;
    const int b = blockIdx.z;
    const int row0 = b * L_SEQ + c * CL;

    if (tid < CL * NST / 4) {   // 64 float4 each
        int row = tid >> 2, q = tid & 3;
        ((float4*)bs)[tid] = *(const float4*)&xdbl[(long)(row0 + row) * E_DIM + 64 + q * 4];
        ((float4*)cs)[tid] = *(const float4*)&xdbl[(long)(row0 + row) * E_DIM + 80 + q * 4];
    }
    __syncthreads();

    float A[16];
#pragma unroll
    for (int q = 0; q < 4; q++) {
        float4 v = *(const float4*)&A_log[(long)d * NST + q * 4];
        A[q * 4 + 0] = -__expf(v.x);
        A[q * 4 + 1] = -__expf(v.y);
        A[q * 4 + 2] = -__expf(v.z);
        A[q * 4 + 3] = -__expf(v.w);
    }
    float h[16];
    const long cb = ((long)(b * NCH + c) * DI + d);
#pragma unroll
    for (int q = 0; q < 4; q++) {
        float4 v = *(const float4*)&hloc[cb * 16 + q * 4];
        h[q * 4 + 0] = v.x; h[q * 4 + 1] = v.y; h[q * 4 + 2] = v.z; h[q * 4 + 3] = v.w;
    }
    const float Dd = Dp[d];

    long idx = (long)row0 * DI + d;
    float d0v = out[idx],      x0v = x[idx];   // out currently holds delta
    float d1v = out[idx + DI], x1v = x[idx + DI];
#pragma unroll
    for (int ll = 0; ll < CL; ll++) {
        float dc = d0v, xc = x0v;
        d0v = d1v; x0v = x1v;
        if (ll + 2 < CL) { d1v = out[idx + 2 * DI]; x1v = x[idx + 2 * DI]; }
        float du = dc * xc;
        float y = 0.f;
#pragma unroll
        for (int q = 0; q < 4; q++) {
            float4 v = *(const float4*)&bs[ll * NST + q * 4];
            float4 w = *(const float4*)&cs[ll * NST + q * 4];
            float e0 = __expf(dc * A[q * 4 + 0]);
            float e1 = __expf(dc * A[q * 4 + 1]);
            float e2 = __expf(dc * A[q * 4 + 2]);
            float e3 = __expf(dc * A[q * 4 + 3]);
            h[q * 4 + 0] = fmaf(e0, h[q * 4 + 0], du * v.x);
            h[q * 4 + 1] = fmaf(e1, h[q * 4 + 1], du * v.y);
            h[q * 4 + 2] = fmaf(e2, h[q * 4 + 2], du * v.z);
            h[q * 4 + 3] = fmaf(e3, h[q * 4 + 3], du * v.w);
            y = fmaf(h[q * 4 + 0], w.x, y);
            y = fmaf(h[q * 4 + 1], w.y, y);
            y = fmaf(h[q * 4 + 2], w.z, y);
            y = fmaf(h[q * 4 + 3], w.w, y);
        }
        out[idx] = fmaf(xc, Dd, y);
        idx += DI;
    }
}

extern "C" void kernel_launch(void* const* d_in, const int* in_sizes, int n_in,
                              void* d_out, int out_size, void* d_ws, size_t ws_size,
                              hipStream_t stream) {
    const float* x    = (const float*)d_in[0];
    const float* Wx   = (const float*)d_in[1];
    const float* Wdt  = (const float*)d_in[2];
    const float* bdt  = (const float*)d_in[3];
    const float* Alog = (const float*)d_in[4];
    const float* Dp   = (const float*)d_in[5];
    float* out = (float*)d_out;
    float* ws = (float*)d_ws;
    float* xdbl  = ws + WS_XDBL;
    float* partb = ws + WS_PART;
    float* hloc  = ws + WS_HLOC;   // overlays partb (disjoint lifetime)
    float* dsumb = ws + WS_DSUM;

    gemm_xproj_part<<<dim3(NROW / 64, SPLITK), 256, 0, stream>>>(x, Wx, partb);
    xproj_reduce<<<dim3(NROW * E_DIM / 4 / 256), 256, 0, stream>>>(partb, xdbl);
    gemm_dt<<<dim3(NROW / 64, DI / 128), 256, 0, stream>>>(xdbl, Wdt, bdt, out);
    scan_carry<<<dim3(DI / 256, NCH, BATCH), 256, 0, stream>>>(x, out, xdbl, Alog, hloc, dsumb);
    scan_prefix<<<dim3(BATCH * DI * NST / 256), 256, 0, stream>>>(Alog, hloc, dsumb);
    scan_out<<<dim3(DI / 256, NCH, BATCH), 256, 0, stream>>>(x, xdbl, Alog, Dp, hloc, out);
}